// Round 19
// baseline (434.914 us; speedup 1.0000x reference)
//
#include <hip/hip_runtime.h>
#include <math.h>

typedef float f32x4 __attribute__((ext_vector_type(4)));
typedef short s16x8 __attribute__((ext_vector_type(8)));
typedef unsigned short u16x4 __attribute__((ext_vector_type(4)));

#define HW 4096
#define CCH 512
#define NK 64
#define EPAD 136   // epilogue LDS row pitch (ushorts)

// ---- ws layout (BYTE offsets) — SIZE-AUDITED ----
#define C_XB   0ULL
#define C_H2   67108864ULL
#define C_H1P  83886080ULL
#define C_X1B  83886080ULL
#define C_YB   0ULL
#define C_AHI  67108864ULL     // bf16 A [16][64][4096] = 8,388,608 (overlays dead h2)
#define C_ASUM 150994944ULL
#define C_GAM  150999040ULL
#define C_MISC 151031808ULL
#define C_W1F  151048192ULL
#define C_W2F  151179264ULL
#define C_W3B  151474176ULL
#define C_WRB  151605248ULL
#define C_WLB  152129536ULL
#define C_PE   152653824ULL    // f32 8,388,608 -> 161,042,432
#define C_CWH  161042432ULL    // bf16 cw [64][512] 65,536 -> end 161,107,968

#define MS_S1 0
#define MS_T1 128
#define MS_S2 256
#define MS_T2 384
#define MS_S3 512
#define MS_T3 1024
#define MS_SR 1536
#define MS_TR 2048
#define MS_SL 2560
#define MS_TL 3072
#define MS_SE 3584
#define MS_TE 3648
#define MS_CSQ 3712

__device__ __forceinline__ float b2f(unsigned short u) {
  unsigned int x = ((unsigned int)u) << 16;
  return __builtin_bit_cast(float, x);
}
__device__ __forceinline__ unsigned short f2b(float f) {
  unsigned int i = __builtin_bit_cast(unsigned int, f);
  i += 0x7fffu + ((i >> 16) & 1u);
  return (unsigned short)(i >> 16);
}

// ---------------- prep ----------------
__global__ void prep_kernel(
    const float* __restrict__ g1, const float* __restrict__ b1, const float* __restrict__ m1, const float* __restrict__ v1,
    const float* __restrict__ g2, const float* __restrict__ b2, const float* __restrict__ m2, const float* __restrict__ v2,
    const float* __restrict__ g3, const float* __restrict__ b3, const float* __restrict__ m3, const float* __restrict__ v3,
    const float* __restrict__ gr, const float* __restrict__ br, const float* __restrict__ mr, const float* __restrict__ vr,
    const float* __restrict__ gl, const float* __restrict__ bl, const float* __restrict__ ml, const float* __restrict__ vl,
    const float* __restrict__ ge, const float* __restrict__ be, const float* __restrict__ me, const float* __restrict__ ve,
    const float* __restrict__ cw, float* __restrict__ misc)
{
  const int t = threadIdx.x;
  if (t < 128) {
    float s = g1[t] * rsqrtf(v1[t] + 1e-6f);
    misc[MS_S1 + t] = s; misc[MS_T1 + t] = b1[t] - m1[t] * s;
    s = g2[t] * rsqrtf(v2[t] + 1e-6f);
    misc[MS_S2 + t] = s; misc[MS_T2 + t] = b2[t] - m2[t] * s;
  }
  for (int c = t; c < 512; c += 256) {
    float s = g3[c] * rsqrtf(v3[c] + 1e-6f);
    misc[MS_S3 + c] = s; misc[MS_T3 + c] = b3[c] - m3[c] * s;
    s = gr[c] * rsqrtf(vr[c] + 1e-6f);
    misc[MS_SR + c] = s; misc[MS_TR + c] = br[c] - mr[c] * s;
    s = gl[c] * rsqrtf(vl[c] + 1e-5f);
    misc[MS_SL + c] = s; misc[MS_TL + c] = bl[c] - ml[c] * s;
  }
  if (t < 64) {
    float s = ge[t] * rsqrtf(ve[t] + 1e-5f);
    misc[MS_SE + t] = s; misc[MS_TE + t] = be[t] - me[t] * s;
    float acc = 0.f;
    for (int c = 0; c < 512; ++c) { float v = cw[t * 512 + c]; acc += v * v; }
    misc[MS_CSQ + t] = acc;
  }
}

// ---------------- fold weights -> bf16 ----------------
__global__ void fold_bf16_kernel(const float* __restrict__ w, const float* __restrict__ s,
                                 unsigned short* __restrict__ out, int total, int kper)
{
  int i = blockIdx.x * 256 + threadIdx.x;
  if (i < total) out[i] = f2b(w[i] * s[i / kper]);
}

__global__ void fold_w2_kernel(const float* __restrict__ w2, const float* __restrict__ s,
                               unsigned short* __restrict__ out)
{
  int j = blockIdx.x * 256 + threadIdx.x;
  if (j < 147456) {
    int m = j / 1152, r = j - m * 1152;
    int tp = r >> 7, ci = r & 127;
    out[j] = f2b(w2[m * 1152 + ci * 9 + tp] * s[m]);
  }
}

// codewords -> single bf16 plane
__global__ void fold_cw_kernel(const float* __restrict__ cw, unsigned short* __restrict__ ch)
{
  int i = blockIdx.x * 256 + threadIdx.x;
  if (i < 32768) ch[i] = f2b(cw[i]);
}

// ---------------- f32 NCHW (512 ch) -> bf16 NHWC ----------------
__global__ __launch_bounds__(256) void tr_kernel(const float* __restrict__ x,
                                                 unsigned short* __restrict__ xb)
{
  __shared__ float T[64][65];
  const int b = blockIdx.z, c0 = blockIdx.y * 64, n0 = blockIdx.x * 64;
  const int t = threadIdx.x;
  const int rr = t >> 4, cc = (t & 15) * 4;
#pragma unroll
  for (int rep = 0; rep < 4; ++rep) {
    const int cr = rep * 16 + rr;
    const float4 v = *(const float4*)(x + ((size_t)(b * 512 + c0 + cr)) * 4096 + n0 + cc);
    T[cr][cc + 0] = v.x; T[cr][cc + 1] = v.y; T[cr][cc + 2] = v.z; T[cr][cc + 3] = v.w;
  }
  __syncthreads();
#pragma unroll
  for (int rep = 0; rep < 4; ++rep) {
    const int nr = rep * 16 + rr;
    u16x4 o;
    o[0] = f2b(T[cc + 0][nr]); o[1] = f2b(T[cc + 1][nr]);
    o[2] = f2b(T[cc + 2][nr]); o[3] = f2b(T[cc + 3][nr]);
    *(u16x4*)(xb + ((size_t)(b * 4096 + n0 + nr)) * 512 + c0 + cc) = o;
  }
}

// ======== MFMA GEMM v3 (R13-verified best): reg-staged dbuf LDS, 1 barrier/chunk ========
template<int BMODE>
__device__ __forceinline__ void run_phase(
    const unsigned short* __restrict__ Wp,
    const unsigned short* __restrict__ Xb,
    const int K, const int tid, const int n0,
    unsigned short* __restrict__ As, unsigned short* __restrict__ Bs,
    f32x4 acc[4][4])
{
  const int lane = tid & 63;
  const int wv = tid >> 6, wm = wv >> 1, wn = wv & 1;

  const int ko = tid & 3;
  const int r0 = tid >> 2;
  const int r1 = 64 + r0;

  const unsigned short* aS0 = Wp + (size_t)r0 * K + ko * 8;
  const unsigned short* aS1 = Wp + (size_t)r1 * K + ko * 8;
  const int slot0 = (((r0 >> 4) * 64) + ko * 16 + (r0 & 15)) * 8;
  const int slot1 = (((r1 >> 4) * 64) + ko * 16 + (r1 & 15)) * 8;

  const unsigned short* bS0 = nullptr;
  const unsigned short* bS1 = nullptr;
  size_t bBase0 = 0, bBase1 = 0;
  if constexpr (BMODE == 0) {
    bS0 = Xb + (size_t)(n0 + r0) * K + ko * 8;
    bS1 = Xb + (size_t)(n0 + r1) * K + ko * 8;
  } else {
    const int pg0 = n0 + r0, pg1 = n0 + r1;
    bBase0 = (size_t)((pg0 >> 6) * 66 + (pg0 & 63)) * 128 + ko * 8;
    bBase1 = (size_t)((pg1 >> 6) * 66 + (pg1 & 63)) * 128 + ko * 8;
  }

  s16x8 a0, a1, b0, b1;
  auto LOADC = [&](int kt) {
    __builtin_memcpy(&a0, aS0 + kt, 16);
    __builtin_memcpy(&a1, aS1 + kt, 16);
    if constexpr (BMODE == 0) {
      __builtin_memcpy(&b0, bS0 + kt, 16);
      __builtin_memcpy(&b1, bS1 + kt, 16);
    } else {
      const int tap = kt >> 7;
      const int ky = tap / 3, kx = tap - ky * 3;
      const int off = (ky * 66 + kx) * 128 + (kt & 127);
      __builtin_memcpy(&b0, Xb + bBase0 + off, 16);
      __builtin_memcpy(&b1, Xb + bBase1 + off, 16);
    }
  };

  LOADC(0);
  *(s16x8*)(As + slot0) = a0; *(s16x8*)(As + slot1) = a1;
  *(s16x8*)(Bs + slot0) = b0; *(s16x8*)(Bs + slot1) = b1;
  __syncthreads();

  int cur = 0;
  for (int kt = 0; kt < K; kt += 32) {
    const bool more = (kt + 32) < K;
    if (more) LOADC(kt + 32);

    const unsigned short* Ac = As + cur * 4096;
    const unsigned short* Bc = Bs + cur * 4096;
    s16x8 afr[4], bfr[4];
#pragma unroll
    for (int i = 0; i < 4; ++i)
      afr[i] = *(const s16x8*)(Ac + (size_t)((wm * 4 + i) * 64 + lane) * 8);
#pragma unroll
    for (int j = 0; j < 4; ++j)
      bfr[j] = *(const s16x8*)(Bc + (size_t)((wn * 4 + j) * 64 + lane) * 8);
#pragma unroll
    for (int i = 0; i < 4; ++i)
#pragma unroll
      for (int j = 0; j < 4; ++j)
        acc[i][j] = __builtin_amdgcn_mfma_f32_16x16x32_bf16(afr[i], bfr[j], acc[i][j], 0, 0, 0);

    if (more) {
      const int nx = (cur ^ 1) * 4096;
      *(s16x8*)(As + nx + slot0) = a0; *(s16x8*)(As + nx + slot1) = a1;
      *(s16x8*)(Bs + nx + slot0) = b0; *(s16x8*)(Bs + nx + slot1) = b1;
    }
    __syncthreads();
    cur ^= 1;
  }
}

template<int BMODE, bool DUAL>
__global__ __launch_bounds__(256) void mgemm_kernel(
    const unsigned short* __restrict__ W0, const unsigned short* __restrict__ X0,
    const int K0, const long long xbs0,
    const unsigned short* __restrict__ W1, const unsigned short* __restrict__ X1,
    const int Kp1, const long long xbs1,
    const float* __restrict__ biasMid, const float* __restrict__ biasOut,
    const int omode, const int reluF, const int ldm,
    unsigned short* __restrict__ outB, const long long obsB)
{
  __shared__ __align__(16) unsigned short smem[128 * EPAD];
  unsigned short* As = smem;
  unsigned short* Bs = smem + 8192;

  const int tid = threadIdx.x;
  const int b = blockIdx.z;
  const int n0 = blockIdx.x * 128;
  const int m0 = blockIdx.y * 128;
  const int lane = tid & 63, wv = tid >> 6, wm = wv >> 1, wn = wv & 1;
  const int q = lane >> 4, mm = lane & 15;

  f32x4 acc[4][4];
#pragma unroll
  for (int i = 0; i < 4; ++i)
#pragma unroll
    for (int j = 0; j < 4; ++j) acc[i][j] = (f32x4){0.f, 0.f, 0.f, 0.f};

  run_phase<BMODE>(W0 + (size_t)m0 * K0, X0 + (size_t)b * xbs0, K0, tid, n0, As, Bs, acc);

  if constexpr (DUAL) {
#pragma unroll
    for (int i = 0; i < 4; ++i) {
      const int mb = m0 + wm * 64 + i * 16 + q * 4;
#pragma unroll
      for (int r = 0; r < 4; ++r) {
        const float bm = biasMid[mb + r];
#pragma unroll
        for (int j = 0; j < 4; ++j) acc[i][j][r] = fmaxf(acc[i][j][r] + bm, 0.f);
      }
    }
    run_phase<0>(W1 + (size_t)m0 * Kp1, X1 + (size_t)b * xbs1, Kp1, tid, n0, As, Bs, acc);
  }

  __syncthreads();
  if (omode == 3) {
#pragma unroll
    for (int i = 0; i < 4; ++i) {
      const int chb = wm * 64 + i * 16 + q * 4;
#pragma unroll
      for (int r = 0; r < 4; ++r) {
        const float bo = biasOut[m0 + chb + r];
#pragma unroll
        for (int j = 0; j < 4; ++j) {
          const int px = wn * 64 + j * 16 + mm;
          float v = acc[i][j][r] + bo;
          if (reluF) v = fmaxf(v, 0.f);
          smem[(size_t)(chb + r) * EPAD + px] = f2b(v);
        }
      }
    }
    __syncthreads();
    const int ch = tid >> 1, half = tid & 1;
    const unsigned short* src = smem + (size_t)ch * EPAD + half * 64;
    unsigned short* dst = outB + (size_t)b * obsB + (size_t)(m0 + ch) * HW + n0 + half * 64;
#pragma unroll
    for (int r = 0; r < 8; ++r) {
      s16x8 v;
      __builtin_memcpy(&v, src + r * 8, 16);
      *(s16x8*)(dst + r * 8) = v;
    }
  } else {
#pragma unroll
    for (int i = 0; i < 4; ++i) {
      const int chb = wm * 64 + i * 16 + q * 4;
      float bo[4];
#pragma unroll
      for (int r = 0; r < 4; ++r) bo[r] = biasOut[m0 + chb + r];
#pragma unroll
      for (int j = 0; j < 4; ++j) {
        const int px = wn * 64 + j * 16 + mm;
        u16x4 o;
#pragma unroll
        for (int r = 0; r < 4; ++r) {
          float v = acc[i][j][r] + bo[r];
          if (reluF) v = fmaxf(v, 0.f);
          o[r] = f2b(v);
        }
        *(u16x4*)(smem + (size_t)px * EPAD + chb) = o;
      }
    }
    __syncthreads();
    const int px = tid >> 1, half = tid & 1;
    const unsigned short* src = smem + (size_t)px * EPAD + half * 64;
    size_t dstoff;
    if (omode == 1) {
      dstoff = (size_t)b * obsB + (size_t)(n0 + px) * ldm + m0 + half * 64;
    } else {
      const int hp = ((n0 + px) >> 6) + 1, wp = ((n0 + px) & 63) + 1;
      dstoff = (size_t)b * obsB + ((size_t)hp * 66 + wp) * 128 + m0 + half * 64;
    }
    unsigned short* dst = outB + dstoff;
#pragma unroll
    for (int r = 0; r < 8; ++r) {
      s16x8 v;
      __builtin_memcpy(&v, src + r * 8, 16);
      *(s16x8*)(dst + r * 8) = v;
    }
  }
}

// ======== assignment via MFMA (single cw plane) + softmax + fused asum ========
__global__ __launch_bounds__(256) void assign_mfma_kernel(
    const unsigned short* __restrict__ Yv,
    const unsigned short* __restrict__ cwh,
    const float* __restrict__ scale, const float* __restrict__ misc,
    unsigned short* __restrict__ Ahi, float* __restrict__ asum)
{
  __shared__ __align__(16) unsigned short Bt[64][36];
  __shared__ float xpart[64][33];
  __shared__ float dist[64][65];
  __shared__ float red[4][64];
  __shared__ float xsq[64];
  __shared__ float scl[64];
  __shared__ float csq[64];
  const int tid = threadIdx.x;
  const int b = blockIdx.y;
  const int n0 = blockIdx.x * 64;
  const int lane = tid & 63, wv = tid >> 6;
  const int q = lane >> 4, mm = lane & 15;
  if (tid < 64) { scl[tid] = scale[tid]; csq[tid] = misc[MS_CSQ + tid]; }

  const int g = tid >> 5, ci = tid & 31;
  const unsigned short* ySrc = Yv + (size_t)b * CCH * HW + (size_t)ci * HW + n0 + g * 8;
  const unsigned short* ahP = cwh + (size_t)(wv * 16 + mm) * 512 + q * 8;

  f32x4 acc[4];
#pragma unroll
  for (int j = 0; j < 4; ++j) acc[j] = (f32x4){0.f, 0.f, 0.f, 0.f};
  float xp[8] = {0.f, 0.f, 0.f, 0.f, 0.f, 0.f, 0.f, 0.f};

  for (int kc = 0; kc < 16; ++kc) {
    s16x8 v8;
    __builtin_memcpy(&v8, ySrc + (size_t)(kc * 32) * HW, 16);
    s16x8 ah;
    __builtin_memcpy(&ah, ahP + kc * 32, 16);
    __syncthreads();
#pragma unroll
    for (int e = 0; e < 8; ++e) {
      Bt[g * 8 + e][ci] = (unsigned short)v8[e];
      const float f = b2f((unsigned short)v8[e]);
      xp[e] += f * f;
    }
    __syncthreads();
#pragma unroll
    for (int j = 0; j < 4; ++j) {
      s16x8 bf;
      __builtin_memcpy(&bf, &Bt[j * 16 + mm][q * 8], 16);
      acc[j] = __builtin_amdgcn_mfma_f32_16x16x32_bf16(ah, bf, acc[j], 0, 0, 0);
    }
  }

  __syncthreads();
#pragma unroll
  for (int e = 0; e < 8; ++e) xpart[g * 8 + e][ci] = xp[e];
  __syncthreads();
  {
    const int px = tid >> 2, part = tid & 3;
    float s = 0.f;
#pragma unroll
    for (int u = 0; u < 8; ++u) s += xpart[px][part * 8 + u];
    red[part][px] = s;
  }
  __syncthreads();
  if (tid < 64) xsq[tid] = red[0][tid] + red[1][tid] + red[2][tid] + red[3][tid];
  __syncthreads();

#pragma unroll
  for (int j = 0; j < 4; ++j) {
    const int n = j * 16 + mm;
#pragma unroll
    for (int r = 0; r < 4; ++r) {
      const int k = wv * 16 + q * 4 + r;
      dist[k][n] = scl[k] * (xsq[n] - 2.f * acc[j][r] + csq[k]);
    }
  }
  __syncthreads();

  const int qq = tid >> 6, n = tid & 63;
  float mx = -3.0e38f;
#pragma unroll
  for (int kk = 0; kk < 16; ++kk) mx = fmaxf(mx, dist[qq * 16 + kk][n]);
  red[qq][n] = mx;
  __syncthreads();
  mx = fmaxf(fmaxf(red[0][n], red[1][n]), fmaxf(red[2][n], red[3][n]));
  __syncthreads();
  float sum = 0.f;
#pragma unroll
  for (int kk = 0; kk < 16; ++kk) {
    const float e = __expf(dist[qq * 16 + kk][n] - mx);
    dist[qq * 16 + kk][n] = e;
    sum += e;
  }
  red[qq][n] = sum;
  __syncthreads();
  sum = red[0][n] + red[1][n] + red[2][n] + red[3][n];
  const float inv = 1.f / sum;
  const size_t base = (size_t)b * NK * HW + n0 + n;
#pragma unroll
  for (int kk = 0; kk < 16; ++kk) {
    const float a = dist[qq * 16 + kk][n] * inv;
    Ahi[base + (size_t)(qq * 16 + kk) * HW] = f2b(a);
    // fused asum: wave (= one qq) reduces over its 64 n-lanes
    float ra = a;
#pragma unroll
    for (int off = 32; off >= 1; off >>= 1) ra += __shfl_down(ra, off, 64);
    if (lane == 0) atomicAdd(&asum[b * 64 + qq * 16 + kk], ra);
  }
}

// ---------------- enc via MFMA (single A plane) ----------------
__global__ __launch_bounds__(256) void enc_mfma_kernel(
    const unsigned short* __restrict__ Ahi,
    const unsigned short* __restrict__ Yv, float* __restrict__ pe)
{
  __shared__ __align__(16) unsigned short AHs[2048];
  __shared__ __align__(16) unsigned short Bs[4096];
  const int tid = threadIdx.x;
  const int ncol = blockIdx.x, nc = blockIdx.y, b = blockIdx.z;
  const int lane = tid & 63, wv = tid >> 6;
  const int q = lane >> 4, mm = lane & 15;

  const int ko = tid & 3;
  const int r  = tid >> 2;
  const size_t aoff = ((size_t)b * NK + r) * HW + nc * 1024 + ko * 8;
  const unsigned short* ahS = Ahi + aoff;
  const int slotA = (((r >> 4) * 64) + ko * 16 + (r & 15)) * 8;
  const unsigned short* b0S = Yv + ((size_t)b * CCH + ncol * 128 + r) * HW + nc * 1024 + ko * 8;
  const unsigned short* b1S = b0S + (size_t)64 * HW;
  const int slotB0 = (((r >> 4) * 64) + ko * 16 + (r & 15)) * 8;
  const int slotB1 = ((((r + 64) >> 4) * 64) + ko * 16 + (r & 15)) * 8;

  f32x4 acc[4][2];
#pragma unroll
  for (int i = 0; i < 4; ++i)
#pragma unroll
    for (int j = 0; j < 2; ++j) acc[i][j] = (f32x4){0.f, 0.f, 0.f, 0.f};

  for (int kt = 0; kt < 1024; kt += 32) {
    s16x8 ah, y0, y1;
    __builtin_memcpy(&ah, ahS + kt, 16);
    __builtin_memcpy(&y0, b0S + kt, 16);
    __builtin_memcpy(&y1, b1S + kt, 16);
    __syncthreads();
    *(s16x8*)(AHs + slotA) = ah;
    *(s16x8*)(Bs + slotB0) = y0;
    *(s16x8*)(Bs + slotB1) = y1;
    __syncthreads();

    s16x8 afh[4], bfr[2];
#pragma unroll
    for (int i = 0; i < 4; ++i)
      afh[i] = *(const s16x8*)(AHs + (size_t)(i * 64 + lane) * 8);
#pragma unroll
    for (int j = 0; j < 2; ++j)
      bfr[j] = *(const s16x8*)(Bs + (size_t)((wv * 2 + j) * 64 + lane) * 8);
#pragma unroll
    for (int i = 0; i < 4; ++i)
#pragma unroll
      for (int j = 0; j < 2; ++j)
        acc[i][j] = __builtin_amdgcn_mfma_f32_16x16x32_bf16(afh[i], bfr[j], acc[i][j], 0, 0, 0);
  }

  float* __restrict__ peb = pe + ((size_t)(b * 4 + nc) * NK) * CCH;
#pragma unroll
  for (int i = 0; i < 4; ++i)
#pragma unroll
    for (int j = 0; j < 2; ++j) {
      const int c = ncol * 128 + (wv * 2 + j) * 16 + mm;
#pragma unroll
      for (int rr = 0; rr < 4; ++rr) {
        const int k = i * 16 + q * 4 + rr;
        peb[(size_t)k * CCH + c] = acc[i][j][rr];
      }
    }
}

// ---------------- en + gate ----------------
__global__ __launch_bounds__(256) void engate_kernel(
    const float* __restrict__ pe, const float* __restrict__ asum, const float* __restrict__ cw,
    const float* __restrict__ misc, const float* __restrict__ wfc, const float* __restrict__ bfc,
    float* __restrict__ gam)
{
  const int b = blockIdx.x;
  const int t = threadIdx.x;
  __shared__ float asum_s[64], se_s[64], te_s[64];
  __shared__ __align__(16) float en_s[512];
  if (t < 64) {
    asum_s[t] = asum[b * 64 + t];
    se_s[t]   = misc[MS_SE + t];
    te_s[t]   = misc[MS_TE + t];
  }
  __syncthreads();
  for (int rep = 0; rep < 2; ++rep) {
    const int c = t + rep * 256;
    float en = 0.f;
    const float* __restrict__ peb = pe + (size_t)b * 4 * NK * CCH + c;
    for (int k = 0; k < 64; ++k) {
      const float ps = peb[(size_t)k * CCH] + peb[(size_t)(64 + k) * CCH] +
                       peb[(size_t)(128 + k) * CCH] + peb[(size_t)(192 + k) * CCH];
      float v = ps - asum_s[k] * cw[k * 512 + c];
      v = v * se_s[k] + te_s[k];
      en += fmaxf(v, 0.f);
    }
    en_s[c] = en * (1.f / 64.f);
  }
  __syncthreads();
  for (int rep = 0; rep < 2; ++rep) {
    const int i = t + rep * 256;
    float a = bfc[i];
    const float4* __restrict__ wrow = (const float4*)(wfc + (size_t)i * 512);
    const float4* __restrict__ ev = (const float4*)en_s;
    for (int j = 0; j < 128; ++j) {
      const float4 w4 = wrow[j];
      const float4 e4 = ev[j];
      a += w4.x * e4.x + w4.y * e4.y + w4.z * e4.z + w4.w * e4.w;
    }
    gam[b * 512 + i] = 1.f / (1.f + __expf(-a));
  }
}

// ---------------- fingate ----------------
__global__ __launch_bounds__(256) void fingate_kernel(
    const unsigned short* __restrict__ x1b, const float* __restrict__ gam,
    float* __restrict__ out)
{
  __shared__ float T[64][65];
  const int b = blockIdx.z, c0 = blockIdx.y * 64, n0 = blockIdx.x * 64;
  const int t = threadIdx.x;
  const int rr = t >> 4, cc = (t & 15) * 4;
#pragma unroll
  for (int rep = 0; rep < 4; ++rep) {
    const int pr = rep * 16 + rr;
    u16x4 v = *(const u16x4*)(x1b + ((size_t)(b * 4096 + n0 + pr)) * 512 + c0 + cc);
    T[cc + 0][pr] = b2f(v[0]);
    T[cc + 1][pr] = b2f(v[1]);
    T[cc + 2][pr] = b2f(v[2]);
    T[cc + 3][pr] = b2f(v[3]);
  }
  __syncthreads();
#pragma unroll
  for (int rep = 0; rep < 4; ++rep) {
    const int cr = rep * 16 + rr;
    const float g = 1.f + gam[b * 512 + c0 + cr];
    float4 o;
    o.x = fmaxf(T[cr][cc + 0] * g, 0.f);
    o.y = fmaxf(T[cr][cc + 1] * g, 0.f);
    o.z = fmaxf(T[cr][cc + 2] * g, 0.f);
    o.w = fmaxf(T[cr][cc + 3] * g, 0.f);
    *(float4*)(out + ((size_t)(b * 512 + c0 + cr)) * 4096 + n0 + cc) = o;
  }
}

extern "C" void kernel_launch(void* const* d_in, const int* in_sizes, int n_in,
                              void* d_out, int out_size, void* d_ws, size_t ws_size,
                              hipStream_t stream)
{
  const float* x  = (const float*)d_in[0];
  const float* w1 = (const float*)d_in[1];
  const float* g1 = (const float*)d_in[2];
  const float* b1 = (const float*)d_in[3];
  const float* m1 = (const float*)d_in[4];
  const float* v1 = (const float*)d_in[5];
  const float* w2 = (const float*)d_in[6];
  const float* g2 = (const float*)d_in[7];
  const float* b2 = (const float*)d_in[8];
  const float* m2 = (const float*)d_in[9];
  const float* v2 = (const float*)d_in[10];
  const float* w3 = (const float*)d_in[11];
  const float* g3 = (const float*)d_in[12];
  const float* b3 = (const float*)d_in[13];
  const float* m3 = (const float*)d_in[14];
  const float* v3 = (const float*)d_in[15];
  const float* wr = (const float*)d_in[16];
  const float* gr = (const float*)d_in[17];
  const float* br = (const float*)d_in[18];
  const float* mr = (const float*)d_in[19];
  const float* vr = (const float*)d_in[20];
  const float* wl = (const float*)d_in[21];
  const float* gl = (const float*)d_in[22];
  const float* bl = (const float*)d_in[23];
  const float* ml = (const float*)d_in[24];
  const float* vl = (const float*)d_in[25];
  const float* cw = (const float*)d_in[26];
  const float* scale = (const float*)d_in[27];
  const float* ge = (const float*)d_in[28];
  const float* be = (const float*)d_in[29];
  const float* me = (const float*)d_in[30];
  const float* ve = (const float*)d_in[31];
  const float* wfc = (const float*)d_in[32];
  const float* bfc = (const float*)d_in[33];

  char* wsb = (char*)d_ws;
  unsigned short* xb  = (unsigned short*)(wsb + C_XB);
  unsigned short* h2  = (unsigned short*)(wsb + C_H2);
  unsigned short* h1p = (unsigned short*)(wsb + C_H1P);
  unsigned short* x1b = (unsigned short*)(wsb + C_X1B);
  unsigned short* yb  = (unsigned short*)(wsb + C_YB);
  unsigned short* Ahi = (unsigned short*)(wsb + C_AHI);
  float* pe   = (float*)(wsb + C_PE);
  float* asum = (float*)(wsb + C_ASUM);
  float* gam  = (float*)(wsb + C_GAM);
  float* misc = (float*)(wsb + C_MISC);
  unsigned short* w1f = (unsigned short*)(wsb + C_W1F);
  unsigned short* w2f = (unsigned short*)(wsb + C_W2F);
  unsigned short* w3b = (unsigned short*)(wsb + C_W3B);
  unsigned short* wrb = (unsigned short*)(wsb + C_WRB);
  unsigned short* wlb = (unsigned short*)(wsb + C_WLB);
  unsigned short* cwh = (unsigned short*)(wsb + C_CWH);

  prep_kernel<<<1, 256, 0, stream>>>(g1, b1, m1, v1, g2, b2, m2, v2, g3, b3, m3, v3,
                                     gr, br, mr, vr, gl, bl, ml, vl, ge, be, me, ve,
                                     cw, misc);
  fold_bf16_kernel<<<256, 256, 0, stream>>>(w1, misc + MS_S1, w1f, 65536, 512);
  fold_w2_kernel<<<576, 256, 0, stream>>>(w2, misc + MS_S2, w2f);
  fold_bf16_kernel<<<256, 256, 0, stream>>>(w3, misc + MS_S3, w3b, 65536, 128);
  fold_bf16_kernel<<<1024, 256, 0, stream>>>(wr, misc + MS_SR, wrb, 262144, 512);
  fold_bf16_kernel<<<1024, 256, 0, stream>>>(wl, misc + MS_SL, wlb, 262144, 512);
  fold_cw_kernel<<<128, 256, 0, stream>>>(cw, cwh);

  tr_kernel<<<dim3(64, 8, 16), 256, 0, stream>>>(x, xb);
  hipMemsetAsync(h1p, 0, 17842176, stream);
  hipMemsetAsync(asum, 0, 4096, stream);

  mgemm_kernel<0, false><<<dim3(32, 1, 16), 256, 0, stream>>>(
      w1f, xb, 512, 4096LL * 512, nullptr, nullptr, 0, 0,
      nullptr, misc + MS_T1, 0, 1, 128, h1p, 4356LL * 128);
  mgemm_kernel<1, false><<<dim3(32, 1, 16), 256, 0, stream>>>(
      w2f, h1p, 1152, 4356LL * 128, nullptr, nullptr, 0, 0,
      nullptr, misc + MS_T2, 1, 1, 128, h2, 4096LL * 128);
  mgemm_kernel<0, true><<<dim3(32, 4, 16), 256, 0, stream>>>(
      w3b, h2, 128, 4096LL * 128, wrb, xb, 512, 4096LL * 512,
      misc + MS_T3, misc + MS_TR, 1, 0, 512, x1b, 4096LL * 512);
  mgemm_kernel<0, false><<<dim3(32, 4, 16), 256, 0, stream>>>(
      wlb, x1b, 512, 4096LL * 512, nullptr, nullptr, 0, 0,
      nullptr, misc + MS_TL, 3, 1, 0, yb, 512LL * 4096);

  assign_mfma_kernel<<<dim3(64, 16), 256, 0, stream>>>(yb, cwh, scale, misc, Ahi, asum);
  enc_mfma_kernel<<<dim3(4, 4, 16), 256, 0, stream>>>(Ahi, yb, pe);
  engate_kernel<<<16, 256, 0, stream>>>(pe, asum, cw, misc, wfc, bfc, gam);
  fingate_kernel<<<dim3(64, 8, 16), 256, 0, stream>>>(x1b, gam, (float*)d_out);
}

// Round 20
// 412.448 us; speedup vs baseline: 1.0545x; 1.0545x over previous
//
#include <hip/hip_runtime.h>
#include <math.h>

typedef float f32x4 __attribute__((ext_vector_type(4)));
typedef short s16x8 __attribute__((ext_vector_type(8)));
typedef unsigned short u16x4 __attribute__((ext_vector_type(4)));

#define HW 4096
#define CCH 512
#define NK 64
#define EPAD 136   // epilogue LDS row pitch (ushorts)

// ---- ws layout (BYTE offsets) — SIZE-AUDITED ----
#define C_XB   0ULL
#define C_H2   67108864ULL
#define C_H1P  83886080ULL
#define C_X1B  83886080ULL
#define C_YB   0ULL
#define C_AHI  67108864ULL     // bf16 A [16][64][4096] = 8,388,608 (overlays dead h2)
#define C_ASUM 150994944ULL
#define C_GAM  150999040ULL
#define C_MISC 151031808ULL
#define C_W1F  151048192ULL
#define C_W2F  151179264ULL
#define C_W3B  151474176ULL
#define C_WRB  151605248ULL
#define C_WLB  152129536ULL
#define C_PE   152653824ULL    // f32 8,388,608 -> 161,042,432
#define C_CWH  161042432ULL    // bf16 cw [64][512] 65,536 -> end 161,107,968

#define MS_S1 0
#define MS_T1 128
#define MS_S2 256
#define MS_T2 384
#define MS_S3 512
#define MS_T3 1024
#define MS_SR 1536
#define MS_TR 2048
#define MS_SL 2560
#define MS_TL 3072
#define MS_SE 3584
#define MS_TE 3648
#define MS_CSQ 3712

__device__ __forceinline__ float b2f(unsigned short u) {
  unsigned int x = ((unsigned int)u) << 16;
  return __builtin_bit_cast(float, x);
}
__device__ __forceinline__ unsigned short f2b(float f) {
  unsigned int i = __builtin_bit_cast(unsigned int, f);
  i += 0x7fffu + ((i >> 16) & 1u);
  return (unsigned short)(i >> 16);
}

// ---------------- prep ----------------
__global__ void prep_kernel(
    const float* __restrict__ g1, const float* __restrict__ b1, const float* __restrict__ m1, const float* __restrict__ v1,
    const float* __restrict__ g2, const float* __restrict__ b2, const float* __restrict__ m2, const float* __restrict__ v2,
    const float* __restrict__ g3, const float* __restrict__ b3, const float* __restrict__ m3, const float* __restrict__ v3,
    const float* __restrict__ gr, const float* __restrict__ br, const float* __restrict__ mr, const float* __restrict__ vr,
    const float* __restrict__ gl, const float* __restrict__ bl, const float* __restrict__ ml, const float* __restrict__ vl,
    const float* __restrict__ ge, const float* __restrict__ be, const float* __restrict__ me, const float* __restrict__ ve,
    const float* __restrict__ cw, float* __restrict__ misc)
{
  const int t = threadIdx.x;
  if (t < 128) {
    float s = g1[t] * rsqrtf(v1[t] + 1e-6f);
    misc[MS_S1 + t] = s; misc[MS_T1 + t] = b1[t] - m1[t] * s;
    s = g2[t] * rsqrtf(v2[t] + 1e-6f);
    misc[MS_S2 + t] = s; misc[MS_T2 + t] = b2[t] - m2[t] * s;
  }
  for (int c = t; c < 512; c += 256) {
    float s = g3[c] * rsqrtf(v3[c] + 1e-6f);
    misc[MS_S3 + c] = s; misc[MS_T3 + c] = b3[c] - m3[c] * s;
    s = gr[c] * rsqrtf(vr[c] + 1e-6f);
    misc[MS_SR + c] = s; misc[MS_TR + c] = br[c] - mr[c] * s;
    s = gl[c] * rsqrtf(vl[c] + 1e-5f);
    misc[MS_SL + c] = s; misc[MS_TL + c] = bl[c] - ml[c] * s;
  }
  if (t < 64) {
    float s = ge[t] * rsqrtf(ve[t] + 1e-5f);
    misc[MS_SE + t] = s; misc[MS_TE + t] = be[t] - me[t] * s;
    float acc = 0.f;
    for (int c = 0; c < 512; ++c) { float v = cw[t * 512 + c]; acc += v * v; }
    misc[MS_CSQ + t] = acc;
  }
}

// ---------------- fold weights -> bf16 ----------------
__global__ void fold_bf16_kernel(const float* __restrict__ w, const float* __restrict__ s,
                                 unsigned short* __restrict__ out, int total, int kper)
{
  int i = blockIdx.x * 256 + threadIdx.x;
  if (i < total) out[i] = f2b(w[i] * s[i / kper]);
}

__global__ void fold_w2_kernel(const float* __restrict__ w2, const float* __restrict__ s,
                               unsigned short* __restrict__ out)
{
  int j = blockIdx.x * 256 + threadIdx.x;
  if (j < 147456) {
    int m = j / 1152, r = j - m * 1152;
    int tp = r >> 7, ci = r & 127;
    out[j] = f2b(w2[m * 1152 + ci * 9 + tp] * s[m]);
  }
}

// codewords -> single bf16 plane
__global__ void fold_cw_kernel(const float* __restrict__ cw, unsigned short* __restrict__ ch)
{
  int i = blockIdx.x * 256 + threadIdx.x;
  if (i < 32768) ch[i] = f2b(cw[i]);
}

// ---------------- f32 NCHW (512 ch) -> bf16 NHWC ----------------
__global__ __launch_bounds__(256) void tr_kernel(const float* __restrict__ x,
                                                 unsigned short* __restrict__ xb)
{
  __shared__ float T[64][65];
  const int b = blockIdx.z, c0 = blockIdx.y * 64, n0 = blockIdx.x * 64;
  const int t = threadIdx.x;
  const int rr = t >> 4, cc = (t & 15) * 4;
#pragma unroll
  for (int rep = 0; rep < 4; ++rep) {
    const int cr = rep * 16 + rr;
    const float4 v = *(const float4*)(x + ((size_t)(b * 512 + c0 + cr)) * 4096 + n0 + cc);
    T[cr][cc + 0] = v.x; T[cr][cc + 1] = v.y; T[cr][cc + 2] = v.z; T[cr][cc + 3] = v.w;
  }
  __syncthreads();
#pragma unroll
  for (int rep = 0; rep < 4; ++rep) {
    const int nr = rep * 16 + rr;
    u16x4 o;
    o[0] = f2b(T[cc + 0][nr]); o[1] = f2b(T[cc + 1][nr]);
    o[2] = f2b(T[cc + 2][nr]); o[3] = f2b(T[cc + 3][nr]);
    *(u16x4*)(xb + ((size_t)(b * 4096 + n0 + nr)) * 512 + c0 + cc) = o;
  }
}

// ======== MFMA GEMM v3 (R13-verified best): reg-staged dbuf LDS, 1 barrier/chunk ========
template<int BMODE>
__device__ __forceinline__ void run_phase(
    const unsigned short* __restrict__ Wp,
    const unsigned short* __restrict__ Xb,
    const int K, const int tid, const int n0,
    unsigned short* __restrict__ As, unsigned short* __restrict__ Bs,
    f32x4 acc[4][4])
{
  const int lane = tid & 63;
  const int wv = tid >> 6, wm = wv >> 1, wn = wv & 1;

  const int ko = tid & 3;
  const int r0 = tid >> 2;
  const int r1 = 64 + r0;

  const unsigned short* aS0 = Wp + (size_t)r0 * K + ko * 8;
  const unsigned short* aS1 = Wp + (size_t)r1 * K + ko * 8;
  const int slot0 = (((r0 >> 4) * 64) + ko * 16 + (r0 & 15)) * 8;
  const int slot1 = (((r1 >> 4) * 64) + ko * 16 + (r1 & 15)) * 8;

  const unsigned short* bS0 = nullptr;
  const unsigned short* bS1 = nullptr;
  size_t bBase0 = 0, bBase1 = 0;
  if constexpr (BMODE == 0) {
    bS0 = Xb + (size_t)(n0 + r0) * K + ko * 8;
    bS1 = Xb + (size_t)(n0 + r1) * K + ko * 8;
  } else {
    const int pg0 = n0 + r0, pg1 = n0 + r1;
    bBase0 = (size_t)((pg0 >> 6) * 66 + (pg0 & 63)) * 128 + ko * 8;
    bBase1 = (size_t)((pg1 >> 6) * 66 + (pg1 & 63)) * 128 + ko * 8;
  }

  s16x8 a0, a1, b0, b1;
  auto LOADC = [&](int kt) {
    __builtin_memcpy(&a0, aS0 + kt, 16);
    __builtin_memcpy(&a1, aS1 + kt, 16);
    if constexpr (BMODE == 0) {
      __builtin_memcpy(&b0, bS0 + kt, 16);
      __builtin_memcpy(&b1, bS1 + kt, 16);
    } else {
      const int tap = kt >> 7;
      const int ky = tap / 3, kx = tap - ky * 3;
      const int off = (ky * 66 + kx) * 128 + (kt & 127);
      __builtin_memcpy(&b0, Xb + bBase0 + off, 16);
      __builtin_memcpy(&b1, Xb + bBase1 + off, 16);
    }
  };

  LOADC(0);
  *(s16x8*)(As + slot0) = a0; *(s16x8*)(As + slot1) = a1;
  *(s16x8*)(Bs + slot0) = b0; *(s16x8*)(Bs + slot1) = b1;
  __syncthreads();

  int cur = 0;
  for (int kt = 0; kt < K; kt += 32) {
    const bool more = (kt + 32) < K;
    if (more) LOADC(kt + 32);

    const unsigned short* Ac = As + cur * 4096;
    const unsigned short* Bc = Bs + cur * 4096;
    s16x8 afr[4], bfr[4];
#pragma unroll
    for (int i = 0; i < 4; ++i)
      afr[i] = *(const s16x8*)(Ac + (size_t)((wm * 4 + i) * 64 + lane) * 8);
#pragma unroll
    for (int j = 0; j < 4; ++j)
      bfr[j] = *(const s16x8*)(Bc + (size_t)((wn * 4 + j) * 64 + lane) * 8);
#pragma unroll
    for (int i = 0; i < 4; ++i)
#pragma unroll
      for (int j = 0; j < 4; ++j)
        acc[i][j] = __builtin_amdgcn_mfma_f32_16x16x32_bf16(afr[i], bfr[j], acc[i][j], 0, 0, 0);

    if (more) {
      const int nx = (cur ^ 1) * 4096;
      *(s16x8*)(As + nx + slot0) = a0; *(s16x8*)(As + nx + slot1) = a1;
      *(s16x8*)(Bs + nx + slot0) = b0; *(s16x8*)(Bs + nx + slot1) = b1;
    }
    __syncthreads();
    cur ^= 1;
  }
}

template<int BMODE, bool DUAL>
__global__ __launch_bounds__(256) void mgemm_kernel(
    const unsigned short* __restrict__ W0, const unsigned short* __restrict__ X0,
    const int K0, const long long xbs0,
    const unsigned short* __restrict__ W1, const unsigned short* __restrict__ X1,
    const int Kp1, const long long xbs1,
    const float* __restrict__ biasMid, const float* __restrict__ biasOut,
    const int omode, const int reluF, const int ldm,
    unsigned short* __restrict__ outB, const long long obsB)
{
  __shared__ __align__(16) unsigned short smem[128 * EPAD];
  unsigned short* As = smem;
  unsigned short* Bs = smem + 8192;

  const int tid = threadIdx.x;
  const int b = blockIdx.z;
  const int n0 = blockIdx.x * 128;
  const int m0 = blockIdx.y * 128;
  const int lane = tid & 63, wv = tid >> 6, wm = wv >> 1, wn = wv & 1;
  const int q = lane >> 4, mm = lane & 15;

  f32x4 acc[4][4];
#pragma unroll
  for (int i = 0; i < 4; ++i)
#pragma unroll
    for (int j = 0; j < 4; ++j) acc[i][j] = (f32x4){0.f, 0.f, 0.f, 0.f};

  run_phase<BMODE>(W0 + (size_t)m0 * K0, X0 + (size_t)b * xbs0, K0, tid, n0, As, Bs, acc);

  if constexpr (DUAL) {
#pragma unroll
    for (int i = 0; i < 4; ++i) {
      const int mb = m0 + wm * 64 + i * 16 + q * 4;
#pragma unroll
      for (int r = 0; r < 4; ++r) {
        const float bm = biasMid[mb + r];
#pragma unroll
        for (int j = 0; j < 4; ++j) acc[i][j][r] = fmaxf(acc[i][j][r] + bm, 0.f);
      }
    }
    run_phase<0>(W1 + (size_t)m0 * Kp1, X1 + (size_t)b * xbs1, Kp1, tid, n0, As, Bs, acc);
  }

  __syncthreads();
  if (omode == 3) {
#pragma unroll
    for (int i = 0; i < 4; ++i) {
      const int chb = wm * 64 + i * 16 + q * 4;
#pragma unroll
      for (int r = 0; r < 4; ++r) {
        const float bo = biasOut[m0 + chb + r];
#pragma unroll
        for (int j = 0; j < 4; ++j) {
          const int px = wn * 64 + j * 16 + mm;
          float v = acc[i][j][r] + bo;
          if (reluF) v = fmaxf(v, 0.f);
          smem[(size_t)(chb + r) * EPAD + px] = f2b(v);
        }
      }
    }
    __syncthreads();
    const int ch = tid >> 1, half = tid & 1;
    const unsigned short* src = smem + (size_t)ch * EPAD + half * 64;
    unsigned short* dst = outB + (size_t)b * obsB + (size_t)(m0 + ch) * HW + n0 + half * 64;
#pragma unroll
    for (int r = 0; r < 8; ++r) {
      s16x8 v;
      __builtin_memcpy(&v, src + r * 8, 16);
      *(s16x8*)(dst + r * 8) = v;
    }
  } else {
#pragma unroll
    for (int i = 0; i < 4; ++i) {
      const int chb = wm * 64 + i * 16 + q * 4;
      float bo[4];
#pragma unroll
      for (int r = 0; r < 4; ++r) bo[r] = biasOut[m0 + chb + r];
#pragma unroll
      for (int j = 0; j < 4; ++j) {
        const int px = wn * 64 + j * 16 + mm;
        u16x4 o;
#pragma unroll
        for (int r = 0; r < 4; ++r) {
          float v = acc[i][j][r] + bo[r];
          if (reluF) v = fmaxf(v, 0.f);
          o[r] = f2b(v);
        }
        *(u16x4*)(smem + (size_t)px * EPAD + chb) = o;
      }
    }
    __syncthreads();
    const int px = tid >> 1, half = tid & 1;
    const unsigned short* src = smem + (size_t)px * EPAD + half * 64;
    size_t dstoff;
    if (omode == 1) {
      dstoff = (size_t)b * obsB + (size_t)(n0 + px) * ldm + m0 + half * 64;
    } else {
      const int hp = ((n0 + px) >> 6) + 1, wp = ((n0 + px) & 63) + 1;
      dstoff = (size_t)b * obsB + ((size_t)hp * 66 + wp) * 128 + m0 + half * 64;
    }
    unsigned short* dst = outB + dstoff;
#pragma unroll
    for (int r = 0; r < 8; ++r) {
      s16x8 v;
      __builtin_memcpy(&v, src + r * 8, 16);
      *(s16x8*)(dst + r * 8) = v;
    }
  }
}

// ======== assignment via MFMA (single cw plane) + softmax -> Ahi ========
__global__ __launch_bounds__(256) void assign_mfma_kernel(
    const unsigned short* __restrict__ Yv,
    const unsigned short* __restrict__ cwh,
    const float* __restrict__ scale, const float* __restrict__ misc,
    unsigned short* __restrict__ Ahi)
{
  __shared__ __align__(16) unsigned short Bt[64][36];
  __shared__ float xpart[64][33];
  __shared__ float dist[64][65];
  __shared__ float red[4][64];
  __shared__ float xsq[64];
  __shared__ float scl[64];
  __shared__ float csq[64];
  const int tid = threadIdx.x;
  const int b = blockIdx.y;
  const int n0 = blockIdx.x * 64;
  const int lane = tid & 63, wv = tid >> 6;
  const int q = lane >> 4, mm = lane & 15;
  if (tid < 64) { scl[tid] = scale[tid]; csq[tid] = misc[MS_CSQ + tid]; }

  const int g = tid >> 5, ci = tid & 31;
  const unsigned short* ySrc = Yv + (size_t)b * CCH * HW + (size_t)ci * HW + n0 + g * 8;
  const unsigned short* ahP = cwh + (size_t)(wv * 16 + mm) * 512 + q * 8;

  f32x4 acc[4];
#pragma unroll
  for (int j = 0; j < 4; ++j) acc[j] = (f32x4){0.f, 0.f, 0.f, 0.f};
  float xp[8] = {0.f, 0.f, 0.f, 0.f, 0.f, 0.f, 0.f, 0.f};

  for (int kc = 0; kc < 16; ++kc) {
    s16x8 v8;
    __builtin_memcpy(&v8, ySrc + (size_t)(kc * 32) * HW, 16);
    s16x8 ah;
    __builtin_memcpy(&ah, ahP + kc * 32, 16);
    __syncthreads();
#pragma unroll
    for (int e = 0; e < 8; ++e) {
      Bt[g * 8 + e][ci] = (unsigned short)v8[e];
      const float f = b2f((unsigned short)v8[e]);
      xp[e] += f * f;
    }
    __syncthreads();
#pragma unroll
    for (int j = 0; j < 4; ++j) {
      s16x8 bf;
      __builtin_memcpy(&bf, &Bt[j * 16 + mm][q * 8], 16);
      acc[j] = __builtin_amdgcn_mfma_f32_16x16x32_bf16(ah, bf, acc[j], 0, 0, 0);
    }
  }

  __syncthreads();
#pragma unroll
  for (int e = 0; e < 8; ++e) xpart[g * 8 + e][ci] = xp[e];
  __syncthreads();
  {
    const int px = tid >> 2, part = tid & 3;
    float s = 0.f;
#pragma unroll
    for (int u = 0; u < 8; ++u) s += xpart[px][part * 8 + u];
    red[part][px] = s;
  }
  __syncthreads();
  if (tid < 64) xsq[tid] = red[0][tid] + red[1][tid] + red[2][tid] + red[3][tid];
  __syncthreads();

#pragma unroll
  for (int j = 0; j < 4; ++j) {
    const int n = j * 16 + mm;
#pragma unroll
    for (int r = 0; r < 4; ++r) {
      const int k = wv * 16 + q * 4 + r;
      dist[k][n] = scl[k] * (xsq[n] - 2.f * acc[j][r] + csq[k]);
    }
  }
  __syncthreads();

  const int qq = tid >> 6, n = tid & 63;
  float mx = -3.0e38f;
#pragma unroll
  for (int kk = 0; kk < 16; ++kk) mx = fmaxf(mx, dist[qq * 16 + kk][n]);
  red[qq][n] = mx;
  __syncthreads();
  mx = fmaxf(fmaxf(red[0][n], red[1][n]), fmaxf(red[2][n], red[3][n]));
  __syncthreads();
  float sum = 0.f;
#pragma unroll
  for (int kk = 0; kk < 16; ++kk) {
    const float e = __expf(dist[qq * 16 + kk][n] - mx);
    dist[qq * 16 + kk][n] = e;
    sum += e;
  }
  red[qq][n] = sum;
  __syncthreads();
  sum = red[0][n] + red[1][n] + red[2][n] + red[3][n];
  const float inv = 1.f / sum;
  const size_t base = (size_t)b * NK * HW + n0 + n;
#pragma unroll
  for (int kk = 0; kk < 16; ++kk)
    Ahi[base + (size_t)(qq * 16 + kk) * HW] = f2b(dist[qq * 16 + kk][n] * inv);
}

// ---------------- asum from single A plane ----------------
__global__ void asum_kernel(const unsigned short* __restrict__ Ahi, float* __restrict__ asum)
{
  const int bk = blockIdx.x;
  const unsigned short* __restrict__ rh = Ahi + (size_t)bk * HW;
  const int t = threadIdx.x;
  float p = 0.f;
  for (int i = t * 8; i < HW; i += 2048) {
    s16x8 h;
    __builtin_memcpy(&h, rh + i, 16);
#pragma unroll
    for (int e = 0; e < 8; ++e) p += b2f((unsigned short)h[e]);
  }
  __shared__ float sm[256];
  sm[t] = p;
  __syncthreads();
  for (int s = 128; s > 0; s >>= 1) {
    if (t < s) sm[t] += sm[t + s];
    __syncthreads();
  }
  if (t == 0) asum[bk] = sm[0];
}

// ---------------- enc via MFMA (single A plane) ----------------
__global__ __launch_bounds__(256) void enc_mfma_kernel(
    const unsigned short* __restrict__ Ahi,
    const unsigned short* __restrict__ Yv, float* __restrict__ pe)
{
  __shared__ __align__(16) unsigned short AHs[2048];
  __shared__ __align__(16) unsigned short Bs[4096];
  const int tid = threadIdx.x;
  const int ncol = blockIdx.x, nc = blockIdx.y, b = blockIdx.z;
  const int lane = tid & 63, wv = tid >> 6;
  const int q = lane >> 4, mm = lane & 15;

  const int ko = tid & 3;
  const int r  = tid >> 2;
  const size_t aoff = ((size_t)b * NK + r) * HW + nc * 1024 + ko * 8;
  const unsigned short* ahS = Ahi + aoff;
  const int slotA = (((r >> 4) * 64) + ko * 16 + (r & 15)) * 8;
  const unsigned short* b0S = Yv + ((size_t)b * CCH + ncol * 128 + r) * HW + nc * 1024 + ko * 8;
  const unsigned short* b1S = b0S + (size_t)64 * HW;
  const int slotB0 = (((r >> 4) * 64) + ko * 16 + (r & 15)) * 8;
  const int slotB1 = ((((r + 64) >> 4) * 64) + ko * 16 + (r & 15)) * 8;

  f32x4 acc[4][2];
#pragma unroll
  for (int i = 0; i < 4; ++i)
#pragma unroll
    for (int j = 0; j < 2; ++j) acc[i][j] = (f32x4){0.f, 0.f, 0.f, 0.f};

  for (int kt = 0; kt < 1024; kt += 32) {
    s16x8 ah, y0, y1;
    __builtin_memcpy(&ah, ahS + kt, 16);
    __builtin_memcpy(&y0, b0S + kt, 16);
    __builtin_memcpy(&y1, b1S + kt, 16);
    __syncthreads();
    *(s16x8*)(AHs + slotA) = ah;
    *(s16x8*)(Bs + slotB0) = y0;
    *(s16x8*)(Bs + slotB1) = y1;
    __syncthreads();

    s16x8 afh[4], bfr[2];
#pragma unroll
    for (int i = 0; i < 4; ++i)
      afh[i] = *(const s16x8*)(AHs + (size_t)(i * 64 + lane) * 8);
#pragma unroll
    for (int j = 0; j < 2; ++j)
      bfr[j] = *(const s16x8*)(Bs + (size_t)((wv * 2 + j) * 64 + lane) * 8);
#pragma unroll
    for (int i = 0; i < 4; ++i)
#pragma unroll
      for (int j = 0; j < 2; ++j)
        acc[i][j] = __builtin_amdgcn_mfma_f32_16x16x32_bf16(afh[i], bfr[j], acc[i][j], 0, 0, 0);
  }

  float* __restrict__ peb = pe + ((size_t)(b * 4 + nc) * NK) * CCH;
#pragma unroll
  for (int i = 0; i < 4; ++i)
#pragma unroll
    for (int j = 0; j < 2; ++j) {
      const int c = ncol * 128 + (wv * 2 + j) * 16 + mm;
#pragma unroll
      for (int rr = 0; rr < 4; ++rr) {
        const int k = i * 16 + q * 4 + rr;
        peb[(size_t)k * CCH + c] = acc[i][j][rr];
      }
    }
}

// ---------------- en + gate ----------------
__global__ __launch_bounds__(256) void engate_kernel(
    const float* __restrict__ pe, const float* __restrict__ asum, const float* __restrict__ cw,
    const float* __restrict__ misc, const float* __restrict__ wfc, const float* __restrict__ bfc,
    float* __restrict__ gam)
{
  const int b = blockIdx.x;
  const int t = threadIdx.x;
  __shared__ float asum_s[64], se_s[64], te_s[64];
  __shared__ __align__(16) float en_s[512];
  if (t < 64) {
    asum_s[t] = asum[b * 64 + t];
    se_s[t]   = misc[MS_SE + t];
    te_s[t]   = misc[MS_TE + t];
  }
  __syncthreads();
  for (int rep = 0; rep < 2; ++rep) {
    const int c = t + rep * 256;
    float en = 0.f;
    const float* __restrict__ peb = pe + (size_t)b * 4 * NK * CCH + c;
    for (int k = 0; k < 64; ++k) {
      const float ps = peb[(size_t)k * CCH] + peb[(size_t)(64 + k) * CCH] +
                       peb[(size_t)(128 + k) * CCH] + peb[(size_t)(192 + k) * CCH];
      float v = ps - asum_s[k] * cw[k * 512 + c];
      v = v * se_s[k] + te_s[k];
      en += fmaxf(v, 0.f);
    }
    en_s[c] = en * (1.f / 64.f);
  }
  __syncthreads();
  for (int rep = 0; rep < 2; ++rep) {
    const int i = t + rep * 256;
    float a = bfc[i];
    const float4* __restrict__ wrow = (const float4*)(wfc + (size_t)i * 512);
    const float4* __restrict__ ev = (const float4*)en_s;
    for (int j = 0; j < 128; ++j) {
      const float4 w4 = wrow[j];
      const float4 e4 = ev[j];
      a += w4.x * e4.x + w4.y * e4.y + w4.z * e4.z + w4.w * e4.w;
    }
    gam[b * 512 + i] = 1.f / (1.f + __expf(-a));
  }
}

// ---------------- fingate ----------------
__global__ __launch_bounds__(256) void fingate_kernel(
    const unsigned short* __restrict__ x1b, const float* __restrict__ gam,
    float* __restrict__ out)
{
  __shared__ float T[64][65];
  const int b = blockIdx.z, c0 = blockIdx.y * 64, n0 = blockIdx.x * 64;
  const int t = threadIdx.x;
  const int rr = t >> 4, cc = (t & 15) * 4;
#pragma unroll
  for (int rep = 0; rep < 4; ++rep) {
    const int pr = rep * 16 + rr;
    u16x4 v = *(const u16x4*)(x1b + ((size_t)(b * 4096 + n0 + pr)) * 512 + c0 + cc);
    T[cc + 0][pr] = b2f(v[0]);
    T[cc + 1][pr] = b2f(v[1]);
    T[cc + 2][pr] = b2f(v[2]);
    T[cc + 3][pr] = b2f(v[3]);
  }
  __syncthreads();
#pragma unroll
  for (int rep = 0; rep < 4; ++rep) {
    const int cr = rep * 16 + rr;
    const float g = 1.f + gam[b * 512 + c0 + cr];
    float4 o;
    o.x = fmaxf(T[cr][cc + 0] * g, 0.f);
    o.y = fmaxf(T[cr][cc + 1] * g, 0.f);
    o.z = fmaxf(T[cr][cc + 2] * g, 0.f);
    o.w = fmaxf(T[cr][cc + 3] * g, 0.f);
    *(float4*)(out + ((size_t)(b * 512 + c0 + cr)) * 4096 + n0 + cc) = o;
  }
}

extern "C" void kernel_launch(void* const* d_in, const int* in_sizes, int n_in,
                              void* d_out, int out_size, void* d_ws, size_t ws_size,
                              hipStream_t stream)
{
  const float* x  = (const float*)d_in[0];
  const float* w1 = (const float*)d_in[1];
  const float* g1 = (const float*)d_in[2];
  const float* b1 = (const float*)d_in[3];
  const float* m1 = (const float*)d_in[4];
  const float* v1 = (const float*)d_in[5];
  const float* w2 = (const float*)d_in[6];
  const float* g2 = (const float*)d_in[7];
  const float* b2 = (const float*)d_in[8];
  const float* m2 = (const float*)d_in[9];
  const float* v2 = (const float*)d_in[10];
  const float* w3 = (const float*)d_in[11];
  const float* g3 = (const float*)d_in[12];
  const float* b3 = (const float*)d_in[13];
  const float* m3 = (const float*)d_in[14];
  const float* v3 = (const float*)d_in[15];
  const float* wr = (const float*)d_in[16];
  const float* gr = (const float*)d_in[17];
  const float* br = (const float*)d_in[18];
  const float* mr = (const float*)d_in[19];
  const float* vr = (const float*)d_in[20];
  const float* wl = (const float*)d_in[21];
  const float* gl = (const float*)d_in[22];
  const float* bl = (const float*)d_in[23];
  const float* ml = (const float*)d_in[24];
  const float* vl = (const float*)d_in[25];
  const float* cw = (const float*)d_in[26];
  const float* scale = (const float*)d_in[27];
  const float* ge = (const float*)d_in[28];
  const float* be = (const float*)d_in[29];
  const float* me = (const float*)d_in[30];
  const float* ve = (const float*)d_in[31];
  const float* wfc = (const float*)d_in[32];
  const float* bfc = (const float*)d_in[33];

  char* wsb = (char*)d_ws;
  unsigned short* xb  = (unsigned short*)(wsb + C_XB);
  unsigned short* h2  = (unsigned short*)(wsb + C_H2);
  unsigned short* h1p = (unsigned short*)(wsb + C_H1P);
  unsigned short* x1b = (unsigned short*)(wsb + C_X1B);
  unsigned short* yb  = (unsigned short*)(wsb + C_YB);
  unsigned short* Ahi = (unsigned short*)(wsb + C_AHI);
  float* pe   = (float*)(wsb + C_PE);
  float* asum = (float*)(wsb + C_ASUM);
  float* gam  = (float*)(wsb + C_GAM);
  float* misc = (float*)(wsb + C_MISC);
  unsigned short* w1f = (unsigned short*)(wsb + C_W1F);
  unsigned short* w2f = (unsigned short*)(wsb + C_W2F);
  unsigned short* w3b = (unsigned short*)(wsb + C_W3B);
  unsigned short* wrb = (unsigned short*)(wsb + C_WRB);
  unsigned short* wlb = (unsigned short*)(wsb + C_WLB);
  unsigned short* cwh = (unsigned short*)(wsb + C_CWH);

  prep_kernel<<<1, 256, 0, stream>>>(g1, b1, m1, v1, g2, b2, m2, v2, g3, b3, m3, v3,
                                     gr, br, mr, vr, gl, bl, ml, vl, ge, be, me, ve,
                                     cw, misc);
  fold_bf16_kernel<<<256, 256, 0, stream>>>(w1, misc + MS_S1, w1f, 65536, 512);
  fold_w2_kernel<<<576, 256, 0, stream>>>(w2, misc + MS_S2, w2f);
  fold_bf16_kernel<<<256, 256, 0, stream>>>(w3, misc + MS_S3, w3b, 65536, 128);
  fold_bf16_kernel<<<1024, 256, 0, stream>>>(wr, misc + MS_SR, wrb, 262144, 512);
  fold_bf16_kernel<<<1024, 256, 0, stream>>>(wl, misc + MS_SL, wlb, 262144, 512);
  fold_cw_kernel<<<128, 256, 0, stream>>>(cw, cwh);

  tr_kernel<<<dim3(64, 8, 16), 256, 0, stream>>>(x, xb);
  hipMemsetAsync(h1p, 0, 17842176, stream);

  mgemm_kernel<0, false><<<dim3(32, 1, 16), 256, 0, stream>>>(
      w1f, xb, 512, 4096LL * 512, nullptr, nullptr, 0, 0,
      nullptr, misc + MS_T1, 0, 1, 128, h1p, 4356LL * 128);
  mgemm_kernel<1, false><<<dim3(32, 1, 16), 256, 0, stream>>>(
      w2f, h1p, 1152, 4356LL * 128, nullptr, nullptr, 0, 0,
      nullptr, misc + MS_T2, 1, 1, 128, h2, 4096LL * 128);
  mgemm_kernel<0, true><<<dim3(32, 4, 16), 256, 0, stream>>>(
      w3b, h2, 128, 4096LL * 128, wrb, xb, 512, 4096LL * 512,
      misc + MS_T3, misc + MS_TR, 1, 0, 512, x1b, 4096LL * 512);
  mgemm_kernel<0, false><<<dim3(32, 4, 16), 256, 0, stream>>>(
      wlb, x1b, 512, 4096LL * 512, nullptr, nullptr, 0, 0,
      nullptr, misc + MS_TL, 3, 1, 0, yb, 512LL * 4096);

  assign_mfma_kernel<<<dim3(64, 16), 256, 0, stream>>>(yb, cwh, scale, misc, Ahi);
  asum_kernel<<<1024, 256, 0, stream>>>(Ahi, asum);
  enc_mfma_kernel<<<dim3(4, 4, 16), 256, 0, stream>>>(Ahi, yb, pe);
  engate_kernel<<<16, 256, 0, stream>>>(pe, asum, cw, misc, wfc, bfc, gam);
  fingate_kernel<<<dim3(64, 8, 16), 256, 0, stream>>>(x1b, gam, (float*)d_out);
}